// Round 9
// baseline (541.294 us; speedup 1.0000x reference)
//
#include <hip/hip_runtime.h>
#include <hip/hip_bf16.h>

// Fused window cross-attention, MI355X gfx950. fp32 in, fp32 out.
// Round 9: TWO x-adjacent windows per block (1024 thr = 16 waves; 8 waves per
// window), each window using the round-8 64KB two-region scheme -> 128KB LDS,
// 16 waves/CU. All HBM lines (64B) are fully covered within one block:
// staging reads full lines, paired out-stores cover both x-halves.
// R1(w): Xa -> Q -> V^T -> O ; R2(w): Xb -> K -> P.  Weights pre-packed bf16.

typedef __bf16 bf16x8 __attribute__((ext_vector_type(8)));
typedef float f32x4 __attribute__((ext_vector_type(4)));
typedef unsigned short u16;
typedef unsigned short u16x8 __attribute__((ext_vector_type(8)));

#define MFMA16(A, B, C) __builtin_amdgcn_mfma_f32_16x16x32_bf16((A), (B), (C), 0, 0, 0)

__device__ __forceinline__ int swzA(int t, int byteInRow) {        // rows of 512B ([64][256] bf16)
    return (t << 9) + (byteInRow ^ ((((t & 7) ^ (t >> 3)) & 7) << 4));
}
__device__ __forceinline__ int swzB(int r, int byteInRow) {        // rows of 128B ([*][64] bf16)
    return (r << 7) + (byteInRow ^ ((((r & 7) ^ (r >> 3)) & 7) << 4));
}
__device__ __forceinline__ u16 bfbits(float x) {
    __bf16 h = (__bf16)x;
    return *(u16*)&h;
}

// ---------------- prep: pack weights into fragment order ----------------
__global__ __launch_bounds__(256) void pack_weights(
    const float* __restrict__ Wq, const float* __restrict__ Wk,
    const float* __restrict__ Wv, const float* __restrict__ Wo,
    __bf16* __restrict__ pk)
{
    int gid = blockIdx.x * 256 + threadIdx.x;   // 0..32767
    int m = gid >> 13;
    int f = gid & 8191;
    const float* W = (m == 0) ? Wq : (m == 1) ? Wk : (m == 2) ? Wv : Wo;
    int q  = f >> 11;
    int kk = (f >> 8) & 7;
    int t16 = (f >> 6) & 3;
    int l  = f & 63;
    int row = (q << 6) + (t16 << 4) + (l & 15);
    int col = (kk << 5) + ((l >> 4) << 3);
    const float* s = W + row * 256 + col;
    f32x4 a = *(const f32x4*)s;
    f32x4 b = *(const f32x4*)(s + 4);
    bf16x8 r;
    r[0] = (__bf16)a[0]; r[1] = (__bf16)a[1]; r[2] = (__bf16)a[2]; r[3] = (__bf16)a[3];
    r[4] = (__bf16)b[0]; r[5] = (__bf16)b[1]; r[6] = (__bf16)b[2]; r[7] = (__bf16)b[3];
    *(bf16x8*)(pk + (size_t)gid * 8) = r;
}

__device__ __forceinline__ bf16x8 loadWP(const __bf16* __restrict__ pk,
                                         int q, int kk, int t16, int l) {
    return *(const bf16x8*)(pk + ((((q << 3) + kk) << 2) + t16) * 512 + (l << 3));
}

__global__ __launch_bounds__(1024, 4) void wca_fused(
    const float* __restrict__ fa, const float* __restrict__ fb,
    const __bf16* __restrict__ WPq, const float* __restrict__ bq,
    const __bf16* __restrict__ WPk, const float* __restrict__ bk,
    const __bf16* __restrict__ WPv, const float* __restrict__ bv,
    const __bf16* __restrict__ WPo, const float* __restrict__ bo,
    float* __restrict__ outg, float* __restrict__ attng)
{
    __shared__ __attribute__((aligned(16))) char S[131072];   // 2 windows x 64KB

    const int tid  = threadIdx.x;
    const int l    = tid & 63;
    const int wid  = tid >> 6;      // wave 0..15
    const int w    = wid >> 3;      // window within pair (0/1)
    const int q    = wid & 3;       // 64-wide output chunk / head id
    const int th   = (wid >> 2) & 1;// token half (0/1)
    const int lrow = l & 15;
    const int kg   = l >> 4;

    char* const R1 = S + (w << 16);          // Xa -> Q -> V^T -> O
    char* const R2 = R1 + 32768;             // Xb -> K -> P

    // block = x-adjacent window pair; batch -> XCD (bid&7)
    const int bid  = blockIdx.x;             // 0..1023
    const int b    = bid & 7;
    const int k    = bid >> 3;               // 0..127: pair within batch
    const int wy   = k >> 3;                 // 0..15
    const int wxp  = k & 7;                  // pair column 0..7
    const int ybase = wy << 3;
    const int xb16  = wxp << 4;              // pair x-origin (16 px)
    const int win0  = (b << 8) + (wy << 4) + (wxp << 1);
    const int xbase = xb16 + (w << 3);       // this wave's window x-origin
    const int win   = win0 + w;              // this wave's window index

    // ---------------- ph1: stage Xa/Xb for BOTH windows (full 64B lines) ----------------
    {
        #pragma unroll
        for (int it = 0; it < 16; ++it) {
            int qd = (it << 10) + tid;          // 0..16383: (f, c, ty, xq)
            int xq = qd & 3;
            int ty = (qd >> 2) & 7;
            int c  = (qd >> 5) & 255;
            int f  = qd >> 13;
            const float* src = f ? fb : fa;
            const float* gp = src + ((((size_t)b * 256 + c) * 128 + ybase + ty) * 128 + xb16 + (xq << 2));
            f32x4 v = *(const f32x4*)gp;
            char* base = S + ((xq >> 1) << 16) + (f ? 32768 : 0);  // window = xq>>1
            #pragma unroll
            for (int e = 0; e < 4; ++e) {
                int x  = (xq << 2) + e;
                int t  = (ty << 3) + (x & 7);
                *(__bf16*)(base + swzA(t, c << 1)) = (__bf16)v[e];
            }
        }
    }
    __syncthreads();   // b1

    // ---------------- ph2: Q = Xa*Wq^T (regs) ----------------
    f32x4 qacc[2][4] = {};
    {
        #pragma unroll
        for (int kk = 0; kk < 8; ++kk) {
            int c0 = (kk << 5) + (kg << 3);
            bf16x8 a0 = *(const bf16x8*)(R1 + swzA((th << 5) + lrow,      c0 << 1));
            bf16x8 a1 = *(const bf16x8*)(R1 + swzA((th << 5) + 16 + lrow, c0 << 1));
            #pragma unroll
            for (int nt = 0; nt < 4; ++nt) {
                bf16x8 bb = loadWP(WPq, q, kk, nt, l);
                qacc[0][nt] = MFMA16(a0, bb, qacc[0][nt]);
                qacc[1][nt] = MFMA16(a1, bb, qacc[1][nt]);
            }
        }
    }
    __syncthreads();   // b2 (all Xa reads done)

    // ---------------- ph3: Q -> R1 ; K,V^T = f(Xb) -> regs (bf16-packed) ----------------
    unsigned kpk[16], vpk[16];
    {
        #pragma unroll
        for (int mt = 0; mt < 2; ++mt) {
            #pragma unroll
            for (int nt = 0; nt < 4; ++nt) {
                int co = (q << 6) + (nt << 4) + lrow;
                float bi = bq[co];
                #pragma unroll
                for (int r = 0; r < 4; ++r) {
                    int t = (th << 5) + (mt << 4) + (kg << 2) + r;
                    *(__bf16*)(R1 + swzA(t, co << 1)) = (__bf16)(qacc[mt][nt][r] + bi);
                }
            }
        }
        {   // K projection
            f32x4 kacc[2][4] = {};
            #pragma unroll
            for (int kk = 0; kk < 8; ++kk) {
                int c0 = (kk << 5) + (kg << 3);
                bf16x8 a0 = *(const bf16x8*)(R2 + swzA((th << 5) + lrow,      c0 << 1));
                bf16x8 a1 = *(const bf16x8*)(R2 + swzA((th << 5) + 16 + lrow, c0 << 1));
                #pragma unroll
                for (int nt = 0; nt < 4; ++nt) {
                    bf16x8 bb = loadWP(WPk, q, kk, nt, l);
                    kacc[0][nt] = MFMA16(a0, bb, kacc[0][nt]);
                    kacc[1][nt] = MFMA16(a1, bb, kacc[1][nt]);
                }
            }
            #pragma unroll
            for (int mt = 0; mt < 2; ++mt) {
                #pragma unroll
                for (int nt = 0; nt < 4; ++nt) {
                    float bi = bk[(q << 6) + (nt << 4) + lrow];
                    kpk[(mt * 4 + nt) * 2 + 0] =
                        (unsigned)bfbits(kacc[mt][nt][0] + bi) |
                        ((unsigned)bfbits(kacc[mt][nt][1] + bi) << 16);
                    kpk[(mt * 4 + nt) * 2 + 1] =
                        (unsigned)bfbits(kacc[mt][nt][2] + bi) |
                        ((unsigned)bfbits(kacc[mt][nt][3] + bi) << 16);
                }
            }
        }
        {   // V^T projection
            f32x4 vacc[4][2] = {};
            #pragma unroll
            for (int kk = 0; kk < 8; ++kk) {
                int c0 = (kk << 5) + (kg << 3);
                bf16x8 bx0 = *(const bf16x8*)(R2 + swzA((th << 5) + lrow,      c0 << 1));
                bf16x8 bx1 = *(const bf16x8*)(R2 + swzA((th << 5) + 16 + lrow, c0 << 1));
                #pragma unroll
                for (int mt = 0; mt < 4; ++mt) {
                    bf16x8 aw = loadWP(WPv, q, kk, mt, l);
                    vacc[mt][0] = MFMA16(aw, bx0, vacc[mt][0]);
                    vacc[mt][1] = MFMA16(aw, bx1, vacc[mt][1]);
                }
            }
            #pragma unroll
            for (int mt = 0; mt < 4; ++mt) {
                #pragma unroll
                for (int nt = 0; nt < 2; ++nt) {
                    u16 w0 = bfbits(vacc[mt][nt][0] + bv[(q << 6) + (mt << 4) + (kg << 2) + 0]);
                    u16 w1 = bfbits(vacc[mt][nt][1] + bv[(q << 6) + (mt << 4) + (kg << 2) + 1]);
                    u16 w2 = bfbits(vacc[mt][nt][2] + bv[(q << 6) + (mt << 4) + (kg << 2) + 2]);
                    u16 w3 = bfbits(vacc[mt][nt][3] + bv[(q << 6) + (mt << 4) + (kg << 2) + 3]);
                    vpk[(mt * 2 + nt) * 2 + 0] = (unsigned)w0 | ((unsigned)w1 << 16);
                    vpk[(mt * 2 + nt) * 2 + 1] = (unsigned)w2 | ((unsigned)w3 << 16);
                }
            }
        }
    }
    __syncthreads();   // b3 (all Xb reads + Q writes done)

    // ---------------- ph4: K -> R2 (over Xb) ----------------
    {
        #pragma unroll
        for (int mt = 0; mt < 2; ++mt) {
            #pragma unroll
            for (int nt = 0; nt < 4; ++nt) {
                int co = (q << 6) + (nt << 4) + lrow;
                #pragma unroll
                for (int r = 0; r < 4; ++r) {
                    int t = (th << 5) + (mt << 4) + (kg << 2) + r;
                    u16 val = (u16)(kpk[(mt * 4 + nt) * 2 + (r >> 1)] >> ((r & 1) * 16));
                    *(u16*)(R2 + swzA(t, co << 1)) = val;
                }
            }
        }
    }
    __syncthreads();   // b4

    // ---------------- ph5: S = Q_h K_h^T, softmax -> ppk regs ----------------
    unsigned ppk[16];
    {
        const int h = q;
        f32x4 s[2][4] = {};
        #pragma unroll
        for (int kk = 0; kk < 2; ++kk) {
            int c0 = (h << 6) + (kk << 5) + (kg << 3);
            bf16x8 a0 = *(const bf16x8*)(R1 + swzA((th << 5) + lrow,      c0 << 1));
            bf16x8 a1 = *(const bf16x8*)(R1 + swzA((th << 5) + 16 + lrow, c0 << 1));
            #pragma unroll
            for (int nt = 0; nt < 4; ++nt) {
                bf16x8 kb = *(const bf16x8*)(R2 + swzA((nt << 4) + lrow, c0 << 1));
                s[0][nt] = MFMA16(a0, kb, s[0][nt]);
                s[1][nt] = MFMA16(a1, kb, s[1][nt]);
            }
        }
        const float CS = 0.125f * 1.44269504f;
        #pragma unroll
        for (int mt = 0; mt < 2; ++mt) {
            #pragma unroll
            for (int r = 0; r < 4; ++r) {
                float mx = fmaxf(fmaxf(s[mt][0][r], s[mt][1][r]),
                                 fmaxf(s[mt][2][r], s[mt][3][r]));
                mx = fmaxf(mx, __shfl_xor(mx, 1));
                mx = fmaxf(mx, __shfl_xor(mx, 2));
                mx = fmaxf(mx, __shfl_xor(mx, 4));
                mx = fmaxf(mx, __shfl_xor(mx, 8));
                float p0 = exp2f((s[mt][0][r] - mx) * CS);
                float p1 = exp2f((s[mt][1][r] - mx) * CS);
                float p2 = exp2f((s[mt][2][r] - mx) * CS);
                float p3 = exp2f((s[mt][3][r] - mx) * CS);
                float sm = (p0 + p1) + (p2 + p3);
                sm += __shfl_xor(sm, 1);
                sm += __shfl_xor(sm, 2);
                sm += __shfl_xor(sm, 4);
                sm += __shfl_xor(sm, 8);
                float inv = 1.0f / sm;
                p0 *= inv; p1 *= inv; p2 *= inv; p3 *= inv;
                ppk[(mt * 4 + r) * 2 + 0] = (unsigned)bfbits(p0) | ((unsigned)bfbits(p1) << 16);
                ppk[(mt * 4 + r) * 2 + 1] = (unsigned)bfbits(p2) | ((unsigned)bfbits(p3) << 16);
            }
        }
    }
    __syncthreads();   // b5 (all Q/K reads done)

    // ---------------- ph6: P -> R2 ([4][64][64]) ; V^T -> R1 ([256][64]) ----------------
    {
        const int h = q;
        #pragma unroll
        for (int mt = 0; mt < 2; ++mt) {
            #pragma unroll
            for (int r = 0; r < 4; ++r) {
                int i = (th << 5) + (mt << 4) + (kg << 2) + r;
                #pragma unroll
                for (int nt = 0; nt < 4; ++nt) {
                    u16 val = (u16)(ppk[(mt * 4 + r) * 2 + (nt >> 1)] >> ((nt & 1) * 16));
                    *(u16*)(R2 + (h << 13) + swzB(i, ((nt << 4) + lrow) << 1)) = val;
                }
            }
        }
        #pragma unroll
        for (int mt = 0; mt < 4; ++mt) {
            #pragma unroll
            for (int r = 0; r < 4; ++r) {
                int vc = (q << 6) + (mt << 4) + (kg << 2) + r;
                #pragma unroll
                for (int nt = 0; nt < 2; ++nt) {
                    int t = (th << 5) + (nt << 4) + lrow;
                    u16 val = (u16)(vpk[(mt * 2 + nt) * 2 + (r >> 1)] >> ((r & 1) * 16));
                    *(u16*)(R1 + swzB(vc, t << 1)) = val;
                }
            }
        }
    }
    __syncthreads();   // b6

    // ---------------- ph7: O = P * V (regs) + attn copy (both windows, coalesced) ----------------
    f32x4 o[2][4] = {};
    {
        const int h = q;
        #pragma unroll
        for (int kk = 0; kk < 2; ++kk) {
            int j0 = (kk << 5) + (kg << 3);
            bf16x8 a0 = *(const bf16x8*)(R2 + (h << 13) + swzB((th << 5) + lrow,      j0 << 1));
            bf16x8 a1 = *(const bf16x8*)(R2 + (h << 13) + swzB((th << 5) + 16 + lrow, j0 << 1));
            #pragma unroll
            for (int dt = 0; dt < 4; ++dt) {
                bf16x8 vb = *(const bf16x8*)(R1 + swzB((h << 6) + (dt << 4) + lrow, j0 << 1));
                o[0][dt] = MFMA16(a0, vb, o[0][dt]);
                o[1][dt] = MFMA16(a1, vb, o[1][dt]);
            }
        }
        // attn: P (LDS bf16) -> global fp32, 32B per lane fully coalesced, both windows
        #pragma unroll
        for (int it = 0; it < 4; ++it) {
            int idx = (it << 10) + tid;                // 0..4095
            int w2  = idx >> 11;
            int rr  = idx & 2047;
            int h2  = rr >> 9;
            int i2  = (rr >> 3) & 63;
            int jb  = (rr & 7) << 3;
            u16x8 v = *(const u16x8*)(S + (w2 << 16) + 32768 + (h2 << 13) + swzB(i2, jb << 1));
            float* dp = attng + ((((size_t)((win0 + w2) << 2) + h2) << 6) + i2) * 64 + jb;
            f32x4 o0, o1;
            #pragma unroll
            for (int e = 0; e < 4; ++e) {
                union { unsigned u; float f; } c0; c0.u = (unsigned)v[e] << 16;
                union { unsigned u; float f; } c1; c1.u = (unsigned)v[4 + e] << 16;
                o0[e] = c0.f; o1[e] = c1.f;
            }
            *(f32x4*)dp = o0;
            *(f32x4*)(dp + 4) = o1;
        }
    }
    __syncthreads();   // b7 (all P/V reads done)

    // ---------------- ph8: O -> R1 ([64][256]) ----------------
    {
        const int h = q;
        #pragma unroll
        for (int mt = 0; mt < 2; ++mt) {
            #pragma unroll
            for (int dt = 0; dt < 4; ++dt) {
                #pragma unroll
                for (int r = 0; r < 4; ++r) {
                    int t = (th << 5) + (mt << 4) + (kg << 2) + r;
                    int c = (h << 6) + (dt << 4) + lrow;
                    *(__bf16*)(R1 + swzA(t, c << 1)) = (__bf16)o[mt][dt][r];
                }
            }
        }
    }
    __syncthreads();   // b8

    // ---------------- ph9: Out^T = Wo * O^T + bo -> global ----------------
    {
        f32x4 acc[4][2] = {};
        #pragma unroll
        for (int kk = 0; kk < 8; ++kk) {
            int k0 = (kk << 5) + (kg << 3);
            bf16x8 b0 = *(const bf16x8*)(R1 + swzA((th << 5) + lrow,      k0 << 1));
            bf16x8 b1 = *(const bf16x8*)(R1 + swzA((th << 5) + 16 + lrow, k0 << 1));
            #pragma unroll
            for (int mt = 0; mt < 4; ++mt) {
                bf16x8 aw = loadWP(WPo, q, kk, mt, l);
                acc[mt][0] = MFMA16(aw, b0, acc[mt][0]);
                acc[mt][1] = MFMA16(aw, b1, acc[mt][1]);
            }
        }
        #pragma unroll
        for (int mt = 0; mt < 4; ++mt) {
            #pragma unroll
            for (int r = 0; r < 4; ++r) {
                int c = (q << 6) + (mt << 4) + (kg << 2) + r;
                float bi = bo[c];
                #pragma unroll
                for (int nt = 0; nt < 2; ++nt) {
                    int t = (th << 5) + (nt << 4) + lrow;
                    int y = ybase + (t >> 3);
                    int x = xbase + (t & 7);
                    size_t off = (((size_t)b * 256 + c) * 128 + y) * 128 + x;
                    outg[off] = acc[mt][nt][r] + bi;
                }
            }
        }
    }
}

extern "C" void kernel_launch(void* const* d_in, const int* in_sizes, int n_in,
                              void* d_out, int out_size, void* d_ws, size_t ws_size,
                              hipStream_t stream) {
    (void)in_sizes; (void)n_in; (void)ws_size; (void)out_size;
    const float* fa = (const float*)d_in[0];
    const float* fb = (const float*)d_in[1];
    const float* Wq = (const float*)d_in[2];
    const float* bq = (const float*)d_in[3];
    const float* Wk = (const float*)d_in[4];
    const float* bk = (const float*)d_in[5];
    const float* Wv = (const float*)d_in[6];
    const float* bv = (const float*)d_in[7];
    const float* Wo = (const float*)d_in[8];
    const float* bo = (const float*)d_in[9];
    float* outg  = (float*)d_out;
    float* attng = outg + (size_t)8 * 256 * 128 * 128;   // out first, then attn (fp32)

    __bf16* pk = (__bf16*)d_ws;                          // 4 x 128KB packed weights
    const __bf16* WPq = pk;
    const __bf16* WPk = pk + 65536;
    const __bf16* WPv = pk + 131072;
    const __bf16* WPo = pk + 196608;

    pack_weights<<<dim3(128), dim3(256), 0, stream>>>(Wq, Wk, Wv, Wo, pk);
    wca_fused<<<dim3(1024), dim3(1024), 0, stream>>>(
        fa, fb, WPq, bq, WPk, bk, WPv, bv, WPo, bo, outg, attng);
}

// Round 11
// 308.518 us; speedup vs baseline: 1.7545x; 1.7545x over previous
//
#include <hip/hip_runtime.h>
#include <hip/hip_bf16.h>

// Fused window cross-attention, MI355X gfx950. fp32 in, fp32 out.
// Round 11 (= round 10 resubmitted; infra failure, kernel never ran):
// round-8 structure; __launch_bounds__(512,2) (NOT ,4 — that capped VGPRs at
// 64 and spilled kpk/vpk/ppk to scratch = the phantom 600+MB of global
// traffic in rounds 7-9). 64KB LDS, 2 blocks/CU, ~110 VGPRs.
// R1(32KB): Xa -> Q -> V^T -> O ; R2(32KB): Xb -> K -> P.

typedef __bf16 bf16x8 __attribute__((ext_vector_type(8)));
typedef float f32x4 __attribute__((ext_vector_type(4)));
typedef unsigned short u16;
typedef unsigned short u16x8 __attribute__((ext_vector_type(8)));

#define MFMA16(A, B, C) __builtin_amdgcn_mfma_f32_16x16x32_bf16((A), (B), (C), 0, 0, 0)

__device__ __forceinline__ int swzA(int t, int byteInRow) {        // rows of 512B ([64][256] bf16)
    return (t << 9) + (byteInRow ^ ((((t & 7) ^ (t >> 3)) & 7) << 4));
}
__device__ __forceinline__ int swzB(int r, int byteInRow) {        // rows of 128B ([*][64] bf16)
    return (r << 7) + (byteInRow ^ ((((r & 7) ^ (r >> 3)) & 7) << 4));
}
__device__ __forceinline__ u16 bfbits(float x) {
    __bf16 h = (__bf16)x;
    return *(u16*)&h;
}

// ---------------- prep: pack weights into fragment order ----------------
__global__ __launch_bounds__(256) void pack_weights(
    const float* __restrict__ Wq, const float* __restrict__ Wk,
    const float* __restrict__ Wv, const float* __restrict__ Wo,
    __bf16* __restrict__ pk)
{
    int gid = blockIdx.x * 256 + threadIdx.x;   // 0..32767
    int m = gid >> 13;
    int f = gid & 8191;
    const float* W = (m == 0) ? Wq : (m == 1) ? Wk : (m == 2) ? Wv : Wo;
    int q  = f >> 11;
    int kk = (f >> 8) & 7;
    int t16 = (f >> 6) & 3;
    int l  = f & 63;
    int row = (q << 6) + (t16 << 4) + (l & 15);
    int col = (kk << 5) + ((l >> 4) << 3);
    const float* s = W + row * 256 + col;
    f32x4 a = *(const f32x4*)s;
    f32x4 b = *(const f32x4*)(s + 4);
    bf16x8 r;
    r[0] = (__bf16)a[0]; r[1] = (__bf16)a[1]; r[2] = (__bf16)a[2]; r[3] = (__bf16)a[3];
    r[4] = (__bf16)b[0]; r[5] = (__bf16)b[1]; r[6] = (__bf16)b[2]; r[7] = (__bf16)b[3];
    *(bf16x8*)(pk + (size_t)gid * 8) = r;
}

__device__ __forceinline__ bf16x8 loadWP(const __bf16* __restrict__ pk,
                                         int q, int kk, int t16, int l) {
    return *(const bf16x8*)(pk + ((((q << 3) + kk) << 2) + t16) * 512 + (l << 3));
}

__global__ __launch_bounds__(512, 2) void wca_fused(
    const float* __restrict__ fa, const float* __restrict__ fb,
    const __bf16* __restrict__ WPq, const float* __restrict__ bq,
    const __bf16* __restrict__ WPk, const float* __restrict__ bk,
    const __bf16* __restrict__ WPv, const float* __restrict__ bv,
    const __bf16* __restrict__ WPo, const float* __restrict__ bo,
    float* __restrict__ outg, float* __restrict__ attng)
{
    __shared__ __attribute__((aligned(16))) char S[65536];
    char* const R1 = S;              // Xa -> Q [64][256] -> V^T [256][64] -> O [64][256]
    char* const R2 = S + 32768;      // Xb -> K [64][256] -> P [4][64][64]

    const int tid  = threadIdx.x;
    const int l    = tid & 63;
    const int wid  = tid >> 6;      // wave 0..7
    const int lrow = l & 15;
    const int kg   = l >> 4;
    const int q    = wid & 3;       // 64-wide output chunk / head id
    const int th   = wid >> 2;      // token half (0/1)

    const int wgid = blockIdx.x;
    const int win  = ((wgid & 7) << 8) | (wgid >> 3);
    const int b    = win >> 8;
    const int wy   = (win >> 4) & 15;
    const int wx   = win & 15;
    const int ybase = wy << 3, xbase = wx << 3;

    // ---------------- ph1: stage Xa -> R1, Xb -> R2 ----------------
    {
        #pragma unroll
        for (int f = 0; f < 2; ++f) {
            const float* src = f ? fb : fa;
            char* dst = f ? R2 : R1;
            #pragma unroll
            for (int it = 0; it < 4; ++it) {
                int idx = (it << 9) + tid;          // 0..2047 = (c, ty)
                int c  = idx >> 3;
                int ty = idx & 7;
                const float* gp = src + ((((size_t)b * 256 + c) * 128 + ybase + ty) * 128 + xbase);
                f32x4 v0 = *(const f32x4*)gp;
                f32x4 v1 = *(const f32x4*)(gp + 4);
                #pragma unroll
                for (int tx = 0; tx < 4; ++tx) {
                    *(__bf16*)(dst + swzA((ty << 3) + tx,     c << 1)) = (__bf16)v0[tx];
                    *(__bf16*)(dst + swzA((ty << 3) + 4 + tx, c << 1)) = (__bf16)v1[tx];
                }
            }
        }
    }
    __syncthreads();   // b1

    // ---------------- ph2: Q = Xa*Wq^T (regs) ----------------
    f32x4 qacc[2][4] = {};
    {
        #pragma unroll
        for (int kk = 0; kk < 8; ++kk) {
            int c0 = (kk << 5) + (kg << 3);
            bf16x8 a0 = *(const bf16x8*)(R1 + swzA((th << 5) + lrow,      c0 << 1));
            bf16x8 a1 = *(const bf16x8*)(R1 + swzA((th << 5) + 16 + lrow, c0 << 1));
            #pragma unroll
            for (int nt = 0; nt < 4; ++nt) {
                bf16x8 bb = loadWP(WPq, q, kk, nt, l);
                qacc[0][nt] = MFMA16(a0, bb, qacc[0][nt]);
                qacc[1][nt] = MFMA16(a1, bb, qacc[1][nt]);
            }
        }
    }
    __syncthreads();   // b2 (all Xa reads done)

    // ---------------- ph3: Q -> R1 ; K,V^T = f(Xb) -> regs (bf16-packed) ----------------
    unsigned kpk[16], vpk[16];
    {
        // Q write (over Xa)
        #pragma unroll
        for (int mt = 0; mt < 2; ++mt) {
            #pragma unroll
            for (int nt = 0; nt < 4; ++nt) {
                int co = (q << 6) + (nt << 4) + lrow;
                float bi = bq[co];
                #pragma unroll
                for (int r = 0; r < 4; ++r) {
                    int t = (th << 5) + (mt << 4) + (kg << 2) + r;
                    *(__bf16*)(R1 + swzA(t, co << 1)) = (__bf16)(qacc[mt][nt][r] + bi);
                }
            }
        }
        // K projection -> kacc -> kpk
        {
            f32x4 kacc[2][4] = {};
            #pragma unroll
            for (int kk = 0; kk < 8; ++kk) {
                int c0 = (kk << 5) + (kg << 3);
                bf16x8 a0 = *(const bf16x8*)(R2 + swzA((th << 5) + lrow,      c0 << 1));
                bf16x8 a1 = *(const bf16x8*)(R2 + swzA((th << 5) + 16 + lrow, c0 << 1));
                #pragma unroll
                for (int nt = 0; nt < 4; ++nt) {
                    bf16x8 bb = loadWP(WPk, q, kk, nt, l);
                    kacc[0][nt] = MFMA16(a0, bb, kacc[0][nt]);
                    kacc[1][nt] = MFMA16(a1, bb, kacc[1][nt]);
                }
            }
            #pragma unroll
            for (int mt = 0; mt < 2; ++mt) {
                #pragma unroll
                for (int nt = 0; nt < 4; ++nt) {
                    float bi = bk[(q << 6) + (nt << 4) + lrow];
                    kpk[(mt * 4 + nt) * 2 + 0] =
                        (unsigned)bfbits(kacc[mt][nt][0] + bi) |
                        ((unsigned)bfbits(kacc[mt][nt][1] + bi) << 16);
                    kpk[(mt * 4 + nt) * 2 + 1] =
                        (unsigned)bfbits(kacc[mt][nt][2] + bi) |
                        ((unsigned)bfbits(kacc[mt][nt][3] + bi) << 16);
                }
            }
        }
        // V^T projection -> vacc -> vpk
        {
            f32x4 vacc[4][2] = {};
            #pragma unroll
            for (int kk = 0; kk < 8; ++kk) {
                int c0 = (kk << 5) + (kg << 3);
                bf16x8 bx0 = *(const bf16x8*)(R2 + swzA((th << 5) + lrow,      c0 << 1));
                bf16x8 bx1 = *(const bf16x8*)(R2 + swzA((th << 5) + 16 + lrow, c0 << 1));
                #pragma unroll
                for (int mt = 0; mt < 4; ++mt) {
                    bf16x8 aw = loadWP(WPv, q, kk, mt, l);
                    vacc[mt][0] = MFMA16(aw, bx0, vacc[mt][0]);
                    vacc[mt][1] = MFMA16(aw, bx1, vacc[mt][1]);
                }
            }
            #pragma unroll
            for (int mt = 0; mt < 4; ++mt) {
                #pragma unroll
                for (int nt = 0; nt < 2; ++nt) {
                    u16 w0 = bfbits(vacc[mt][nt][0] + bv[(q << 6) + (mt << 4) + (kg << 2) + 0]);
                    u16 w1 = bfbits(vacc[mt][nt][1] + bv[(q << 6) + (mt << 4) + (kg << 2) + 1]);
                    u16 w2 = bfbits(vacc[mt][nt][2] + bv[(q << 6) + (mt << 4) + (kg << 2) + 2]);
                    u16 w3 = bfbits(vacc[mt][nt][3] + bv[(q << 6) + (mt << 4) + (kg << 2) + 3]);
                    vpk[(mt * 2 + nt) * 2 + 0] = (unsigned)w0 | ((unsigned)w1 << 16);
                    vpk[(mt * 2 + nt) * 2 + 1] = (unsigned)w2 | ((unsigned)w3 << 16);
                }
            }
        }
    }
    __syncthreads();   // b3 (all Xb reads + Q writes done)

    // ---------------- ph4: K -> R2 (over Xb) ----------------
    {
        #pragma unroll
        for (int mt = 0; mt < 2; ++mt) {
            #pragma unroll
            for (int nt = 0; nt < 4; ++nt) {
                int co = (q << 6) + (nt << 4) + lrow;
                #pragma unroll
                for (int r = 0; r < 4; ++r) {
                    int t = (th << 5) + (mt << 4) + (kg << 2) + r;
                    u16 val = (u16)(kpk[(mt * 4 + nt) * 2 + (r >> 1)] >> ((r & 1) * 16));
                    *(u16*)(R2 + swzA(t, co << 1)) = val;
                }
            }
        }
    }
    __syncthreads();   // b4

    // ---------------- ph5: S = Q_h K_h^T, softmax -> ppk regs ----------------
    unsigned ppk[16];
    {
        const int h = q;
        f32x4 s[2][4] = {};
        #pragma unroll
        for (int kk = 0; kk < 2; ++kk) {
            int c0 = (h << 6) + (kk << 5) + (kg << 3);
            bf16x8 a0 = *(const bf16x8*)(R1 + swzA((th << 5) + lrow,      c0 << 1));
            bf16x8 a1 = *(const bf16x8*)(R1 + swzA((th << 5) + 16 + lrow, c0 << 1));
            #pragma unroll
            for (int nt = 0; nt < 4; ++nt) {
                bf16x8 kb = *(const bf16x8*)(R2 + swzA((nt << 4) + lrow, c0 << 1));
                s[0][nt] = MFMA16(a0, kb, s[0][nt]);
                s[1][nt] = MFMA16(a1, kb, s[1][nt]);
            }
        }
        const float CS = 0.125f * 1.44269504f;
        #pragma unroll
        for (int mt = 0; mt < 2; ++mt) {
            #pragma unroll
            for (int r = 0; r < 4; ++r) {
                float mx = fmaxf(fmaxf(s[mt][0][r], s[mt][1][r]),
                                 fmaxf(s[mt][2][r], s[mt][3][r]));
                mx = fmaxf(mx, __shfl_xor(mx, 1));
                mx = fmaxf(mx, __shfl_xor(mx, 2));
                mx = fmaxf(mx, __shfl_xor(mx, 4));
                mx = fmaxf(mx, __shfl_xor(mx, 8));
                float p0 = exp2f((s[mt][0][r] - mx) * CS);
                float p1 = exp2f((s[mt][1][r] - mx) * CS);
                float p2 = exp2f((s[mt][2][r] - mx) * CS);
                float p3 = exp2f((s[mt][3][r] - mx) * CS);
                float sm = (p0 + p1) + (p2 + p3);
                sm += __shfl_xor(sm, 1);
                sm += __shfl_xor(sm, 2);
                sm += __shfl_xor(sm, 4);
                sm += __shfl_xor(sm, 8);
                float inv = 1.0f / sm;
                p0 *= inv; p1 *= inv; p2 *= inv; p3 *= inv;
                ppk[(mt * 4 + r) * 2 + 0] = (unsigned)bfbits(p0) | ((unsigned)bfbits(p1) << 16);
                ppk[(mt * 4 + r) * 2 + 1] = (unsigned)bfbits(p2) | ((unsigned)bfbits(p3) << 16);
            }
        }
    }
    __syncthreads();   // b5 (all Q/K reads done)

    // ---------------- ph6: P -> R2 ([4][64][64]) ; V^T -> R1 ([256][64]) ----------------
    {
        const int h = q;
        #pragma unroll
        for (int mt = 0; mt < 2; ++mt) {
            #pragma unroll
            for (int r = 0; r < 4; ++r) {
                int i = (th << 5) + (mt << 4) + (kg << 2) + r;
                #pragma unroll
                for (int nt = 0; nt < 4; ++nt) {
                    u16 val = (u16)(ppk[(mt * 4 + r) * 2 + (nt >> 1)] >> ((nt & 1) * 16));
                    *(u16*)(R2 + (h << 13) + swzB(i, ((nt << 4) + lrow) << 1)) = val;
                }
            }
        }
        #pragma unroll
        for (int mt = 0; mt < 4; ++mt) {
            #pragma unroll
            for (int r = 0; r < 4; ++r) {
                int vc = (q << 6) + (mt << 4) + (kg << 2) + r;
                #pragma unroll
                for (int nt = 0; nt < 2; ++nt) {
                    int t = (th << 5) + (nt << 4) + lrow;
                    u16 val = (u16)(vpk[(mt * 2 + nt) * 2 + (r >> 1)] >> ((r & 1) * 16));
                    *(u16*)(R1 + swzB(vc, t << 1)) = val;
                }
            }
        }
    }
    __syncthreads();   // b6

    // ---------------- ph7: O = P * V (regs) + attn copy (LDS -> global, coalesced) ----------------
    f32x4 o[2][4] = {};
    {
        const int h = q;
        #pragma unroll
        for (int kk = 0; kk < 2; ++kk) {
            int j0 = (kk << 5) + (kg << 3);
            bf16x8 a0 = *(const bf16x8*)(R2 + (h << 13) + swzB((th << 5) + lrow,      j0 << 1));
            bf16x8 a1 = *(const bf16x8*)(R2 + (h << 13) + swzB((th << 5) + 16 + lrow, j0 << 1));
            #pragma unroll
            for (int dt = 0; dt < 4; ++dt) {
                bf16x8 vb = *(const bf16x8*)(R1 + swzB((h << 6) + (dt << 4) + lrow, j0 << 1));
                o[0][dt] = MFMA16(a0, vb, o[0][dt]);
                o[1][dt] = MFMA16(a1, vb, o[1][dt]);
            }
        }
        // attn: P (LDS bf16) -> global fp32, 32B per lane fully coalesced
        #pragma unroll
        for (int it = 0; it < 4; ++it) {
            int idx = (it << 9) + tid;                 // 0..2047
            int h2 = idx >> 9;
            int i2 = (idx >> 3) & 63;
            int jb = (idx & 7) << 3;
            u16x8 v = *(const u16x8*)(R2 + (h2 << 13) + swzB(i2, jb << 1));
            float* dp = attng + ((((size_t)(win << 2) + h2) << 6) + i2) * 64 + jb;
            f32x4 o0, o1;
            #pragma unroll
            for (int e = 0; e < 4; ++e) {
                union { unsigned u; float f; } c0; c0.u = (unsigned)v[e] << 16;
                union { unsigned u; float f; } c1; c1.u = (unsigned)v[4 + e] << 16;
                o0[e] = c0.f; o1[e] = c1.f;
            }
            *(f32x4*)dp = o0;
            *(f32x4*)(dp + 4) = o1;
        }
    }
    __syncthreads();   // b7 (all P/V reads done)

    // ---------------- ph8: O -> R1 ([64][256]) ----------------
    {
        const int h = q;
        #pragma unroll
        for (int mt = 0; mt < 2; ++mt) {
            #pragma unroll
            for (int dt = 0; dt < 4; ++dt) {
                #pragma unroll
                for (int r = 0; r < 4; ++r) {
                    int t = (th << 5) + (mt << 4) + (kg << 2) + r;
                    int c = (h << 6) + (dt << 4) + lrow;
                    *(__bf16*)(R1 + swzA(t, c << 1)) = (__bf16)o[mt][dt][r];
                }
            }
        }
    }
    __syncthreads();   // b8

    // ---------------- ph9: Out^T = Wo * O^T + bo -> global ----------------
    {
        f32x4 acc[4][2] = {};
        #pragma unroll
        for (int kk = 0; kk < 8; ++kk) {
            int k0 = (kk << 5) + (kg << 3);
            bf16x8 b0 = *(const bf16x8*)(R1 + swzA((th << 5) + lrow,      k0 << 1));
            bf16x8 b1 = *(const bf16x8*)(R1 + swzA((th << 5) + 16 + lrow, k0 << 1));
            #pragma unroll
            for (int mt = 0; mt < 4; ++mt) {
                bf16x8 aw = loadWP(WPo, q, kk, mt, l);
                acc[mt][0] = MFMA16(aw, b0, acc[mt][0]);
                acc[mt][1] = MFMA16(aw, b1, acc[mt][1]);
            }
        }
        #pragma unroll
        for (int mt = 0; mt < 4; ++mt) {
            #pragma unroll
            for (int r = 0; r < 4; ++r) {
                int c = (q << 6) + (mt << 4) + (kg << 2) + r;
                float bi = bo[c];
                #pragma unroll
                for (int nt = 0; nt < 2; ++nt) {
                    int t = (th << 5) + (nt << 4) + lrow;
                    int y = ybase + (t >> 3);
                    int x = xbase + (t & 7);
                    size_t off = (((size_t)b * 256 + c) * 128 + y) * 128 + x;
                    outg[off] = acc[mt][nt][r] + bi;
                }
            }
        }
    }
}

extern "C" void kernel_launch(void* const* d_in, const int* in_sizes, int n_in,
                              void* d_out, int out_size, void* d_ws, size_t ws_size,
                              hipStream_t stream) {
    (void)in_sizes; (void)n_in; (void)ws_size; (void)out_size;
    const float* fa = (const float*)d_in[0];
    const float* fb = (const float*)d_in[1];
    const float* Wq = (const float*)d_in[2];
    const float* bq = (const float*)d_in[3];
    const float* Wk = (const float*)d_in[4];
    const float* bk = (const float*)d_in[5];
    const float* Wv = (const float*)d_in[6];
    const float* bv = (const float*)d_in[7];
    const float* Wo = (const float*)d_in[8];
    const float* bo = (const float*)d_in[9];
    float* outg  = (float*)d_out;
    float* attng = outg + (size_t)8 * 256 * 128 * 128;   // out first, then attn (fp32)

    __bf16* pk = (__bf16*)d_ws;                          // 4 x 128KB packed weights
    const __bf16* WPq = pk;
    const __bf16* WPk = pk + 65536;
    const __bf16* WPv = pk + 131072;
    const __bf16* WPo = pk + 196608;

    pack_weights<<<dim3(128), dim3(256), 0, stream>>>(Wq, Wk, Wv, Wo, pk);
    wca_fused<<<dim3(2048), dim3(512), 0, stream>>>(
        fa, fb, WPq, bq, WPk, bk, WPv, bv, WPo, bo, outg, attng);
}